// Round 4
// baseline (157.364 us; speedup 1.0000x reference)
//
#include <hip/hip_runtime.h>
#include <cmath>

typedef unsigned short u16;
typedef unsigned int   u32;
typedef __attribute__((ext_vector_type(8)))  short short8;
typedef __attribute__((ext_vector_type(4)))  float f32x4;
typedef __attribute__((ext_vector_type(16))) float f32x16;

constexpr int BT    = 32;
constexpr int NTOK  = 512;
constexpr int DIM   = 256;
constexpr int HID   = 256;
constexpr int M_ROWS = BT * NTOK;             // 16384
constexpr int HM     = M_ROWS * 32;           // per-head elems in head-major QKV
constexpr size_t TENS = (size_t)M_ROWS * HID;
constexpr float LAMBDA_INIT  = 0.35550906759096927f;
constexpr float ONE_MINUS_LI = 0.6444909324090307f;
constexpr float LN_EPS = 1e-5f;
constexpr float QSCALE = 0.36067376022224085f;  // 0.25 * log2(e): folded into Q

#define MFMA16(a, b, c) __builtin_amdgcn_mfma_f32_16x16x32_bf16((a), (b), (c), 0, 0, 0)
#define MFMA32(a, b, c) __builtin_amdgcn_mfma_f32_32x32x16_bf16((a), (b), (c), 0, 0, 0)

__device__ __forceinline__ u16 f2bf(float f) {   // RNE
    u32 u = __float_as_uint(f);
    return (u16)((u + 0x7FFFu + ((u >> 16) & 1u)) >> 16);
}

__device__ __forceinline__ float fexp2(float x) {
#if defined(__has_builtin) && __has_builtin(__builtin_amdgcn_exp2f)
    return __builtin_amdgcn_exp2f(x);
#else
    return exp2f(x);
#endif
}

// pack two f32 -> two bf16 (truncate) in one dword: a in low half. HW-validated perm.
__device__ __forceinline__ u32 pack_trunc(float a, float b) {
    return __builtin_amdgcn_perm(__float_as_uint(b), __float_as_uint(a), 0x07060302u);
}

// ---------------------------------------------------------------------------
// prep_w: transpose + convert W (f32 [k][n]) -> Wt (bf16 [n][k]), 3 matrices
// ---------------------------------------------------------------------------
__global__ __launch_bounds__(256) void prep_w(const float* __restrict__ Wq,
                                              const float* __restrict__ Wk,
                                              const float* __restrict__ Wv,
                                              u16* __restrict__ Wt) {
    const float* W = (blockIdx.z == 0) ? Wq : (blockIdx.z == 1) ? Wk : Wv;
    u16* dst = Wt + (size_t)blockIdx.z * 65536;
    __shared__ float T[64][65];
    const int k0 = blockIdx.x * 64, n0 = blockIdx.y * 64;
    const int tr = threadIdx.x >> 4;
    const int tc = threadIdx.x & 15;
    #pragma unroll
    for (int i = 0; i < 4; ++i) {
        int row = tr + i * 16;
        float4 v = *(const float4*)&W[(size_t)(k0 + row) * HID + n0 + tc * 4];
        T[row][tc * 4 + 0] = v.x; T[row][tc * 4 + 1] = v.y;
        T[row][tc * 4 + 2] = v.z; T[row][tc * 4 + 3] = v.w;
    }
    __syncthreads();
    #pragma unroll
    for (int i = 0; i < 4; ++i) {
        int n = tr + i * 16;
        int k4 = tc * 4;
        uint2 pk;
        pk.x = (u32)f2bf(T[k4 + 0][n]) | ((u32)f2bf(T[k4 + 1][n]) << 16);
        pk.y = (u32)f2bf(T[k4 + 2][n]) | ((u32)f2bf(T[k4 + 3][n]) << 16);
        *(uint2*)&dst[(size_t)(n0 + n) * DIM + k0 + k4] = pk;
    }
}

// ---------------------------------------------------------------------------
// proj: fused QKV GEMM, software-pipelined (register prefetch of next K-tile).
// Tile 64x64, BK=64, 4 waves each 32x32. Head-major bf16 output; Q pre-scaled.
// grid (4, 256): n fastest so consecutive blocks share the x tile (L2 reuse).
// ---------------------------------------------------------------------------
__global__ __launch_bounds__(256, 3) void proj_kernel(
    const float* __restrict__ x, const u16* __restrict__ Wt,
    u16* __restrict__ Qh, u16* __restrict__ Kh, u16* __restrict__ Vh)
{
    __shared__ u16 As[64 * 72];      // [m][k], stride 72
    __shared__ u16 Bs[3][64 * 72];   // [n][k] per z

    const int tid  = threadIdx.x;
    const int n0   = blockIdx.x * 64;
    const int m0   = blockIdx.y * 64;
    const int lane = tid & 63;
    const int wv   = tid >> 6;
    const int q16  = lane & 15;
    const int quad = lane >> 4;
    const int mw   = (wv >> 1) * 32;
    const int nw   = (wv & 1) * 32;

    const int sr = tid >> 2;          // 0..63 staging row
    const int sc = (tid & 3) * 16;    // 0,16,32,48 (u16 elems within 64-k)

    f32x4 acc[3][4];
    #pragma unroll
    for (int z = 0; z < 3; ++z)
        #pragma unroll
        for (int t = 0; t < 4; ++t)
            acc[z][t] = (f32x4){0.f, 0.f, 0.f, 0.f};

    // prefetch registers
    float4 ga[4];
    uint4  gb[3][2];
    {
        const float4* xs = (const float4*)&x[(size_t)(m0 + sr) * DIM + sc];
        ga[0] = xs[0]; ga[1] = xs[1]; ga[2] = xs[2]; ga[3] = xs[3];
        #pragma unroll
        for (int z = 0; z < 3; ++z) {
            const uint4* ws4 = (const uint4*)&Wt[(size_t)z * 65536 + (size_t)(n0 + sr) * DIM + sc];
            gb[z][0] = ws4[0]; gb[z][1] = ws4[1];
        }
    }

    for (int it = 0; it < 4; ++it) {
        // pack prefetched A -> LDS
        {
            uint4 o0, o1;
            o0.x = (u32)f2bf(ga[0].x) | ((u32)f2bf(ga[0].y) << 16);
            o0.y = (u32)f2bf(ga[0].z) | ((u32)f2bf(ga[0].w) << 16);
            o0.z = (u32)f2bf(ga[1].x) | ((u32)f2bf(ga[1].y) << 16);
            o0.w = (u32)f2bf(ga[1].z) | ((u32)f2bf(ga[1].w) << 16);
            o1.x = (u32)f2bf(ga[2].x) | ((u32)f2bf(ga[2].y) << 16);
            o1.y = (u32)f2bf(ga[2].z) | ((u32)f2bf(ga[2].w) << 16);
            o1.z = (u32)f2bf(ga[3].x) | ((u32)f2bf(ga[3].y) << 16);
            o1.w = (u32)f2bf(ga[3].z) | ((u32)f2bf(ga[3].w) << 16);
            *(uint4*)&As[sr * 72 + sc]     = o0;
            *(uint4*)&As[sr * 72 + sc + 8] = o1;
            #pragma unroll
            for (int z = 0; z < 3; ++z) {
                *(uint4*)&Bs[z][sr * 72 + sc]     = gb[z][0];
                *(uint4*)&Bs[z][sr * 72 + sc + 8] = gb[z][1];
            }
        }
        __syncthreads();

        // prefetch next K-tile into registers (overlaps MFMA below)
        if (it < 3) {
            const int kk = (it + 1) * 64;
            const float4* xs = (const float4*)&x[(size_t)(m0 + sr) * DIM + kk + sc];
            ga[0] = xs[0]; ga[1] = xs[1]; ga[2] = xs[2]; ga[3] = xs[3];
            #pragma unroll
            for (int z = 0; z < 3; ++z) {
                const uint4* ws4 = (const uint4*)&Wt[(size_t)z * 65536 + (size_t)(n0 + sr) * DIM + kk + sc];
                gb[z][0] = ws4[0]; gb[z][1] = ws4[1];
            }
        }

        #pragma unroll
        for (int kc = 0; kc < 2; ++kc) {
            short8 a0 = *(const short8*)&As[(mw +      q16) * 72 + kc * 32 + quad * 8];
            short8 a1 = *(const short8*)&As[(mw + 16 + q16) * 72 + kc * 32 + quad * 8];
            #pragma unroll
            for (int z = 0; z < 3; ++z) {
                short8 b0 = *(const short8*)&Bs[z][(nw +      q16) * 72 + kc * 32 + quad * 8];
                short8 b1 = *(const short8*)&Bs[z][(nw + 16 + q16) * 72 + kc * 32 + quad * 8];
                acc[z][0] = MFMA16(a0, b0, acc[z][0]);
                acc[z][1] = MFMA16(a0, b1, acc[z][1]);
                acc[z][2] = MFMA16(a1, b0, acc[z][2]);
                acc[z][3] = MFMA16(a1, b1, acc[z][3]);
            }
        }
        __syncthreads();
    }

    // epilogue: head-major store. C/D: col=lane&15, row=quad*4+reg
    const int hcol = (n0 + nw) >> 5;
    #pragma unroll
    for (int z = 0; z < 3; ++z) {
        u16* C = (z == 0) ? Qh : (z == 1) ? Kh : Vh;
        u16* base = C + (size_t)hcol * HM;
        const float s = (z == 0) ? QSCALE : 1.0f;
        #pragma unroll
        for (int r = 0; r < 4; ++r) {
            const int row = m0 + mw + quad * 4 + r;
            base[(size_t)row * 32 + q16]              = f2bf(acc[z][0][r] * s);
            base[(size_t)row * 32 + q16 + 16]         = f2bf(acc[z][1][r] * s);
            base[(size_t)(row + 16) * 32 + q16]       = f2bf(acc[z][2][r] * s);
            base[(size_t)(row + 16) * 32 + q16 + 16]  = f2bf(acc[z][3][r] * s);
        }
    }
}

// ---------------------------------------------------------------------------
// attn: 32x32x16 MFMA attention (K=16 native -> no wasted K-half).
// grid (4, 8, 32) = (q-quarter, head, bt); 256 threads (4 waves), 32 q/wave.
// QK: S^T = MFMA32(A=K-frag[m=key], B=Q-frag[n=q]); D: col=lane&31=q,
// row=(reg&3)+8*(reg>>2)+4*(lane>>5)=key  [C/D verified m74/m101].
// PV: O = MFMA32(A=P[m=q], B=V^T[n=dim]); D: col=dim, row=q.
// Single per-wave P buffer, reused softmax1 -> softmax2 (same-wave lgkmcnt).
// ---------------------------------------------------------------------------
__global__ __launch_bounds__(256, 3) void attn_kernel(
    const u16* __restrict__ Qh, const u16* __restrict__ Kh, const u16* __restrict__ Vh,
    const float* __restrict__ lq1, const float* __restrict__ lk1,
    const float* __restrict__ lq2, const float* __restrict__ lk2,
    const float* __restrict__ gamma, const float* __restrict__ beta,
    float* __restrict__ out)
{
    __shared__ u16 Ks[256 * 40];     // [key][dim0..31], stride 40 (80B)
    __shared__ u16 Vts[32 * 264];    // [dim][key0..255], stride 264
    __shared__ u16 Pb[4][32 * 40];   // per-wave P [q0..31][key0..31], stride 40

    const int qh  = blockIdx.x;   // 0..3 (128 q rows each)
    const int h   = blockIdx.y;   // 0..7
    const int bt  = blockIdx.z;   // 0..31
    const int tid = threadIdx.x;
    const int lane = tid & 63;
    const int wv   = tid >> 6;
    const int l31  = lane & 31;
    const int hi   = lane >> 5;

    // lambda (uniform scalar path)
    float sa = 0.f, sb = 0.f;
    #pragma unroll
    for (int d = 0; d < 16; ++d) { sa += lq1[d] * lk1[d]; sb += lq2[d] * lk2[d]; }
    const float lam = __expf(sa) - __expf(sb) + LAMBDA_INIT;

    // persistent Q B-fragments: n=q=lane&31, k=(lane>>5)*8+j
    const int qbase = bt * NTOK + qh * 128 + wv * 32;
    const u16* qrowp = Qh + (size_t)h * HM + (size_t)(qbase + l31) * 32 + hi * 8;
    const short8 B1 = *(const short8*)qrowp;          // Q1 dims 0..15
    const short8 B2 = *(const short8*)(qrowp + 16);   // Q2 dims 16..31

    const f32x16 z16 = {0.f,0.f,0.f,0.f,0.f,0.f,0.f,0.f,0.f,0.f,0.f,0.f,0.f,0.f,0.f,0.f};
    f32x16 O1 = z16, O2 = z16;
    float l1 = 0.f, l2 = 0.f;
    u16* P = &Pb[wv][0];

    for (int chunk = 0; chunk < 2; ++chunk) {
        if (chunk) __syncthreads();   // drain previous chunk's LDS reads
        // ---- stage K chunk: 256 rows, one per thread (64B/lane contiguous) ----
        {
            const uint4* src = (const uint4*)(Kh + (size_t)h * HM +
                                (size_t)(bt * NTOK + chunk * 256 + tid) * 32);
            uint4* dst = (uint4*)&Ks[tid * 40];
            dst[0] = src[0]; dst[1] = src[1]; dst[2] = src[2]; dst[3] = src[3];
        }
        // ---- stage V chunk transposed: threads 0..127, 2 keys each ----
        if (tid < 128) {
            const int j0 = tid * 2;
            const u16* v0 = Vh + (size_t)h * HM + (size_t)(bt * NTOK + chunk * 256 + j0) * 32;
            union U { uint4 q[4]; u32 w[16]; } ra, rb;
            #pragma unroll
            for (int i = 0; i < 4; ++i) {
                ra.q[i] = ((const uint4*)v0)[i];
                rb.q[i] = ((const uint4*)(v0 + 32))[i];
            }
            #pragma unroll
            for (int w = 0; w < 16; ++w) {
                u32 lo = __builtin_amdgcn_perm(rb.w[w], ra.w[w], 0x05040100u); // dim 2w
                u32 hi2 = __builtin_amdgcn_perm(rb.w[w], ra.w[w], 0x07060302u); // dim 2w+1
                *(u32*)&Vts[(2 * w)     * 264 + j0] = lo;
                *(u32*)&Vts[(2 * w + 1) * 264 + j0] = hi2;
            }
        }
        __syncthreads();

        for (int kc = 0; kc < 8; ++kc) {   // 32 keys per iter
            // K A-fragments: m=key=lane&31, k=(lane>>5)*8+j
            const u16* krow = &Ks[(kc * 32 + l31) * 40 + hi * 8];
            const short8 A1 = *(const short8*)krow;          // dims 0..15
            const short8 A2 = *(const short8*)(krow + 16);   // dims 16..31
            // V^T B-fragments: n=dim=lane&31, k=key offset (shared by both softmaxes)
            const u16* vrow = &Vts[l31 * 264 + kc * 32 + hi * 8];
            const short8 Vt0 = *(const short8*)vrow;         // keys 0..15 of tile
            const short8 Vt1 = *(const short8*)(vrow + 16);  // keys 16..31

            // ---- softmax 1 ----
            f32x16 S = MFMA32(A1, B1, z16);
            #pragma unroll
            for (int rg = 0; rg < 4; ++rg) {
                float e0 = fexp2(S[4 * rg + 0]);
                float e1 = fexp2(S[4 * rg + 1]);
                float e2 = fexp2(S[4 * rg + 2]);
                float e3 = fexp2(S[4 * rg + 3]);
                l1 += (e0 + e1) + (e2 + e3);
                uint2 w; w.x = pack_trunc(e0, e1); w.y = pack_trunc(e2, e3);
                *(uint2*)&P[l31 * 40 + rg * 8 + hi * 4] = w;
            }
            {
                const short8 P0  = *(const short8*)&P[l31 * 40 + hi * 8];
                const short8 P1f = *(const short8*)&P[l31 * 40 + 16 + hi * 8];
                O1 = MFMA32(P0,  Vt0, O1);
                O1 = MFMA32(P1f, Vt1, O1);
            }
            // ---- softmax 2 (reuse P buffer) ----
            S = MFMA32(A2, B2, z16);
            #pragma unroll
            for (int rg = 0; rg < 4; ++rg) {
                float e0 = fexp2(S[4 * rg + 0]);
                float e1 = fexp2(S[4 * rg + 1]);
                float e2 = fexp2(S[4 * rg + 2]);
                float e3 = fexp2(S[4 * rg + 3]);
                l2 += (e0 + e1) + (e2 + e3);
                uint2 w; w.x = pack_trunc(e0, e1); w.y = pack_trunc(e2, e3);
                *(uint2*)&P[l31 * 40 + rg * 8 + hi * 4] = w;
            }
            {
                const short8 P0  = *(const short8*)&P[l31 * 40 + hi * 8];
                const short8 P1f = *(const short8*)&P[l31 * 40 + 16 + hi * 8];
                O2 = MFMA32(P0,  Vt0, O2);
                O2 = MFMA32(P1f, Vt1, O2);
            }
        }
    }

    // ---- epilogue ----
    l1 += __shfl_xor(l1, 32);
    l2 += __shfl_xor(l2, 32);
    const float i1base = 1.0f / l1;   // for q = l31
    const float i2base = 1.0f / l2;
    const float g = gamma[l31];
    const float bc = beta[l31];

    #pragma unroll
    for (int r = 0; r < 16; ++r) {
        const int qloc = (r & 3) + 8 * (r >> 2) + 4 * hi;   // this reg's q row
        const float i1 = __shfl(i1base, qloc);
        const float i2 = __shfl(i2base, qloc);
        float y = O1[r] * i1 - lam * (O2[r] * i2);

        // LayerNorm over 32 dims: dims live in lanes (l31) within each 32-half
        float s  = y;
        float s2 = y * y;
        #pragma unroll
        for (int off = 1; off < 32; off <<= 1) {
            s  += __shfl_xor(s,  off);
            s2 += __shfl_xor(s2, off);
        }
        const float mu   = s * (1.0f / 32.0f);
        const float var  = s2 * (1.0f / 32.0f) - mu * mu;
        const float rstd = rsqrtf(var + LN_EPS);

        const int row = qbase + qloc;
        out[(size_t)row * HID + h * 32 + l31] = ((y - mu) * rstd * g + bc) * ONE_MINUS_LI;
    }
}

// ---------------------------------------------------------------------------
extern "C" void kernel_launch(void* const* d_in, const int* in_sizes, int n_in,
                              void* d_out, int out_size, void* d_ws, size_t ws_size,
                              hipStream_t stream) {
    const float* x   = (const float*)d_in[0];
    const float* Wq  = (const float*)d_in[1];
    const float* Wk  = (const float*)d_in[2];
    const float* Wv  = (const float*)d_in[3];
    const float* lq1 = (const float*)d_in[4];
    const float* lk1 = (const float*)d_in[5];
    const float* lq2 = (const float*)d_in[6];
    const float* lk2 = (const float*)d_in[7];
    const float* gam = (const float*)d_in[8];
    const float* bet = (const float*)d_in[9];
    float* out = (float*)d_out;

    u16* ws = (u16*)d_ws;
    u16* Wt = ws;                 // 3 * 65536
    u16* Qh = Wt + 3 * 65536;     // head-major [8][16384][32]
    u16* Kh = Qh + TENS;
    u16* Vh = Kh + TENS;

    hipLaunchKernelGGL(prep_w, dim3(4, 4, 3), dim3(256), 0, stream, Wq, Wk, Wv, Wt);
    hipLaunchKernelGGL(proj_kernel, dim3(HID / 64, M_ROWS / 64), dim3(256), 0, stream,
                       x, Wt, Qh, Kh, Vh);
    hipLaunchKernelGGL(attn_kernel, dim3(4, 8, 32), dim3(256), 0, stream,
                       Qh, Kh, Vh, lq1, lk1, lq2, lk2, gam, bet, out);
}